// Round 17
// baseline (136.404 us; speedup 1.0000x reference)
//
#include <hip/hip_runtime.h>
#include <hip/hip_bf16.h>

#define N_NODES 262144
#define N_GRAPHS 256
#define DMODEL 256
#define LN2 0.6931471805599453094

typedef __attribute__((ext_vector_type(4))) float f32x4;
typedef __attribute__((ext_vector_type(8))) short short8;

__device__ __forceinline__ short bf(float x) {
    __hip_bfloat16 h = __float2bfloat16(x);
    return __builtin_bit_cast(short, h);
}

__device__ __forceinline__ short8 cvt8(f32x4 lo, f32x4 hi) {
    short8 a;
    a[0] = bf(lo[0]); a[1] = bf(lo[1]); a[2] = bf(lo[2]); a[3] = bf(lo[3]);
    a[4] = bf(hi[0]); a[5] = bf(hi[1]); a[6] = bf(hi[2]); a[7] = bf(hi[3]);
    return a;
}

__device__ __forceinline__ void mfma4(short8 a, const char* bb, f32x4* acc) {
#pragma unroll
    for (int nt = 0; nt < 4; ++nt) {
        short8 bfrag = *reinterpret_cast<const short8*>(bb + nt * 1024);
        acc[nt] = __builtin_amdgcn_mfma_f32_16x16x32_bf16(a, bfrag, acc[nt], 0, 0, 0);
    }
}

// l2 = log2(1 + 2^(log2e*min(r,64)));  softplus(r) = ln2 * l2 (exact)
__device__ __forceinline__ void elem(float r, int col, int bv,
                                     float& Sl2, float& Sl2p, float& Spr) {
    float t = fminf(r, 64.f) * 1.44269504f;
    float l2 = __log2f(1.f + exp2f(t));
    Sl2 += l2;
    float m = (col == bv) ? 1.f : 0.f;
    Sl2p = fmaf(m, l2, Sl2p);
    Spr = fmaf(m, r, Spr);
}

// R17: dose-response on phase-drifted block concurrency (R15's only win:
// 2 blocks/CU -> 84us). Now 32KB LDS = QUARTER of B (64 cols) -> 1024
// blocks x 256 thr -> 4 independent blocks/CU. Per-wave = R15 structure
// scaled: 16r x 64c, acc[4], group-of-4-ks named-slot pipeline, 16 passes.
// XCD-quad swizzle: rg=(bid>>5)*8+(bid&7), cq=(bid>>3)&3 -> the 4
// col-quarters of the same 1024 rows land adjacently on the SAME XCD ->
// A fetched from HBM once, served 4x from that XCD's L2.
__global__ __launch_bounds__(256, 1) void mvgrl_main(
    const float* __restrict__ l_enc, const float* __restrict__ g_enc,
    const int* __restrict__ batch, double* __restrict__ partials) {
    extern __shared__ char lds_raw[];  // 32KB: quarter of B, fragment order

    const int tid = threadIdx.x;
    const int lane = tid & 63;
    const int wave = tid >> 6;   // 0..3 = row stripe (16 rows each)
    const int bid = blockIdx.x;

    const int rg = (bid >> 5) * 8 + (bid & 7);  // row group 0..255
    const int cq = (bid >> 3) & 3;              // column quarter
    const int row_blk = rg * 1024;
    const int kofs = (lane >> 4) * 8;

    // ---- pass-0 A-slot preloads first (warm pipeline) ----
    f32x4 s0l, s0h, s1l, s1h, s2l, s2h, s3l, s3h;
    const float* arow = l_enc +
        (size_t)(row_blk + wave * 16 + (lane & 15)) * DMODEL + kofs;
    s0l = *reinterpret_cast<const f32x4*>(arow + 0);
    s0h = *reinterpret_cast<const f32x4*>(arow + 4);
    s1l = *reinterpret_cast<const f32x4*>(arow + 32);
    s1h = *reinterpret_cast<const f32x4*>(arow + 36);
    s2l = *reinterpret_cast<const f32x4*>(arow + 64);
    s2h = *reinterpret_cast<const f32x4*>(arow + 68);
    s3l = *reinterpret_cast<const f32x4*>(arow + 96);
    s3h = *reinterpret_cast<const f32x4*>(arow + 100);

    // ---- in-block B pack: our 64 cols of g_enc -> LDS fragment order ----
    // chunk c = ks*4 + nt (32 chunks, 1KB); within chunk lane*16B.
    {
        short8* lb = reinterpret_cast<short8*>(lds_raw);
#pragma unroll 2
        for (int i = 0; i < 8; ++i) {
            int c = wave + i * 4;          // 0..31
            int nt = c & 3, ks = c >> 2;
            int g = cq * 64 + nt * 16 + (lane & 15);
            int k = ks * 32 + (lane >> 4) * 8;
            const float* src = g_enc + g * DMODEL + k;
            f32x4 lo = *reinterpret_cast<const f32x4*>(src);
            f32x4 hi = *reinterpret_cast<const f32x4*>(src + 4);
            lb[c * 64 + lane] = cvt8(lo, hi);
        }
    }
    __syncthreads();
    // no further barriers until final reduction

    const char* ldsB = lds_raw + lane * 16;
    double dS0 = 0.0, dS1 = 0.0, dS2 = 0.0;

#pragma unroll 1
    for (int pass = 0; pass < 16; ++pass) {
        const int rowbase = row_blk + pass * 64 + wave * 16;
        const int rsub = (lane >> 4) * 4;
        int bv0 = batch[rowbase + rsub + 0];
        int bv1 = batch[rowbase + rsub + 1];
        int bv2 = batch[rowbase + rsub + 2];
        int bv3 = batch[rowbase + rsub + 3];

        const float* arow_next = l_enc +
            (size_t)(row_blk + ((pass + 1) & 15) * 64 + wave * 16 + (lane & 15)) *
                DMODEL + kofs;

        f32x4 acc[4];
#pragma unroll
        for (int n = 0; n < 4; ++n) acc[n] = (f32x4){0.f, 0.f, 0.f, 0.f};

#pragma unroll 1
        for (int g = 0; g < 2; ++g) {
            // group g consumes ks g*4..g*4+3; refills: g0 -> this pass
            // ks4..7, g1 -> next pass ks0..3.
            const float* src = (g == 0) ? (arow + 128) : arow_next;
            const char* lb = ldsB + (size_t)g * 4 * 4096;
            {
                short8 a = cvt8(s0l, s0h);
                s0l = *reinterpret_cast<const f32x4*>(src + 0);
                s0h = *reinterpret_cast<const f32x4*>(src + 4);
                mfma4(a, lb + 0 * 4096, acc);
            }
            {
                short8 a = cvt8(s1l, s1h);
                s1l = *reinterpret_cast<const f32x4*>(src + 32);
                s1h = *reinterpret_cast<const f32x4*>(src + 36);
                mfma4(a, lb + 1 * 4096, acc);
            }
            {
                short8 a = cvt8(s2l, s2h);
                s2l = *reinterpret_cast<const f32x4*>(src + 64);
                s2h = *reinterpret_cast<const f32x4*>(src + 68);
                mfma4(a, lb + 2 * 4096, acc);
            }
            {
                short8 a = cvt8(s3l, s3h);
                s3l = *reinterpret_cast<const f32x4*>(src + 96);
                s3h = *reinterpret_cast<const f32x4*>(src + 100);
                mfma4(a, lb + 3 * 4096, acc);
            }
        }
        arow = arow_next;

        // ---- lean epilogue (log2 units) ----
        // C/D: col = cq*64 + nt*16 + (lane&15), row = rowbase + rsub + rg
        float Sl2 = 0.f, Sl2p = 0.f, Spr = 0.f;
        const int colbase = cq * 64 + (lane & 15);
#pragma unroll
        for (int nt = 0; nt < 4; ++nt) {
            const int col = colbase + nt * 16;
            f32x4 av = acc[nt];
            elem(av[0], col, bv0, Sl2, Sl2p, Spr);
            elem(av[1], col, bv1, Sl2, Sl2p, Spr);
            elem(av[2], col, bv2, Sl2, Sl2p, Spr);
            elem(av[3], col, bv3, Sl2, Sl2p, Spr);
        }
        dS0 += (double)Sl2;
        dS1 += (double)Sl2p;
        dS2 += (double)Spr;
    }

    // ---- reduction: wave shuffle -> LDS -> block partial ----
#pragma unroll
    for (int off = 32; off; off >>= 1) {
        dS0 += __shfl_xor(dS0, off);
        dS1 += __shfl_xor(dS1, off);
        dS2 += __shfl_xor(dS2, off);
    }
    __syncthreads();  // everyone done reading B before LDS reuse
    double* red = reinterpret_cast<double*>(lds_raw);
    if (lane == 0) {
        red[wave * 3 + 0] = dS0;
        red[wave * 3 + 1] = dS1;
        red[wave * 3 + 2] = dS2;
    }
    __syncthreads();
    if (tid == 0) {
        double a = 0, b = 0, c = 0;
#pragma unroll
        for (int w = 0; w < 4; ++w) {
            a += red[w * 3 + 0];
            b += red[w * 3 + 1];
            c += red[w * 3 + 2];
        }
        partials[bid * 3 + 0] = a;   // sum log2(1+2^t) (all)
        partials[bid * 3 + 1] = b;   // sum log2(1+2^t) (pos)
        partials[bid * 3 + 2] = c;   // sum r           (pos)
    }
}

__global__ void finalize_kernel(const double* __restrict__ p,
                                float* __restrict__ out) {
    int t = threadIdx.x;  // 1024 threads, one partial-triple each
    double a = p[t * 3 + 0], b = p[t * 3 + 1], c = p[t * 3 + 2];
#pragma unroll
    for (int off = 32; off; off >>= 1) {
        a += __shfl_xor(a, off);
        b += __shfl_xor(b, off);
        c += __shfl_xor(c, off);
    }
    __shared__ double red[48];
    int lane = t & 63, w = t >> 6;
    if (lane == 0) { red[w * 3] = a; red[w * 3 + 1] = b; red[w * 3 + 2] = c; }
    __syncthreads();
    if (t == 0) {
        double A = 0, B = 0, C = 0;
#pragma unroll
        for (int i = 0; i < 16; ++i) {
            A += red[i * 3]; B += red[i * 3 + 1]; C += red[i * 3 + 2];
        }
        const double NN = (double)N_NODES, GG = (double)N_GRAPHS;
        double Sall_q = LN2 * A - NN * GG * LN2;
        double Spq = LN2 * B - NN * LN2;
        double Spr = C;
        double neg = (Sall_q - Spq) / (NN * (GG - 1.0));
        double pos = (Spr - Spq) / NN;
        out[0] = (float)(neg - pos);
    }
}

extern "C" void kernel_launch(void* const* d_in, const int* in_sizes, int n_in,
                              void* d_out, int out_size, void* d_ws,
                              size_t ws_size, hipStream_t stream) {
    const float* l_enc = (const float*)d_in[0];
    const float* g_enc = (const float*)d_in[1];
    const int* batch = (const int*)d_in[2];
    float* out = (float*)d_out;

    double* partials = (double*)d_ws;   // 1024*3 doubles

    (void)hipFuncSetAttribute(reinterpret_cast<const void*>(mvgrl_main),
                              hipFuncAttributeMaxDynamicSharedMemorySize, 32768);

    mvgrl_main<<<1024, 256, 32768, stream>>>(l_enc, g_enc, batch, partials);
    finalize_kernel<<<1, 1024, 0, stream>>>(partials, out);
}

// Round 18
// 124.730 us; speedup vs baseline: 1.0936x; 1.0936x over previous
//
#include <hip/hip_runtime.h>
#include <hip/hip_bf16.h>

#define N_NODES 262144
#define N_GRAPHS 256
#define DMODEL 256
#define LN2 0.6931471805599453094
#define ROW_STRIDE 1040  // 1024B row + 16B pad: row*1040 % 128 = 16*row -> frag reads 2-way (free)

typedef __attribute__((ext_vector_type(4))) float f32x4;
typedef __attribute__((ext_vector_type(8))) short short8;

__device__ __forceinline__ short bf(float x) {
    __hip_bfloat16 h = __float2bfloat16(x);
    return __builtin_bit_cast(short, h);
}

__device__ __forceinline__ short8 cvt8(f32x4 lo, f32x4 hi) {
    short8 a;
    a[0] = bf(lo[0]); a[1] = bf(lo[1]); a[2] = bf(lo[2]); a[3] = bf(lo[3]);
    a[4] = bf(hi[0]); a[5] = bf(hi[1]); a[6] = bf(hi[2]); a[7] = bf(hi[3]);
    return a;
}

// l2 = log2(1 + 2^(log2e*min(r,64)));  softplus(r) = ln2 * l2 (exact)
__device__ __forceinline__ void elem(float r, int col, int bv,
                                     float& Sl2, float& Sl2p, float& Spr) {
    float t = fminf(r, 64.f) * 1.44269504f;
    float l2 = __log2f(1.f + exp2f(t));
    Sl2 += l2;
    float m = (col == bv) ? 1.f : 0.f;
    Sl2p = fmaf(m, l2, Sl2p);
    Spr = fmaf(m, r, Spr);
}

// R18: tall-skinny-GEMM-correct staging.
//  - B RESIDENT IN REGISTERS: each wave owns 64 cols x K=256 as 32 named
//    short8 frags (128 VGPRs). Zero LDS traffic for B.
//  - A staged through LDS: block = 4 waves SHARING the same 16 rows/pass
//    (each wave a different 64-col slice) -> A read ONCE from HBM.
//    T14 split: issue next tile's global loads early, ds_write after the
//    compute, one barrier per pass. Row pad 1040B -> 2-way (free) banks.
//  - 512 blocks x 256 thr, ~195 VGPR -> 2 waves/SIMD -> 2 phase-drifted
//    blocks/CU (R15's confirmed win) with ZERO A-duplication (R17 lesson).
__global__ __launch_bounds__(256, 1) void mvgrl_main(
    const float* __restrict__ l_enc, const float* __restrict__ g_enc,
    const int* __restrict__ batch, double* __restrict__ partials) {
    extern __shared__ char lds_raw[];  // 2 x 16 x 1040 = 33280 B

    const int tid = threadIdx.x;
    const int lane = tid & 63;
    const int wave = tid >> 6;   // 0..3 = owner of cols [wave*64, wave*64+64)
    const int bid = blockIdx.x;
    const int row_blk = bid * 512;

    // ---- B -> registers: 32 frags (ks 0..7 x nt 0..3), 128 VGPRs ----
    short8 b0_0, b0_1, b0_2, b0_3, b1_0, b1_1, b1_2, b1_3;
    short8 b2_0, b2_1, b2_2, b2_3, b3_0, b3_1, b3_2, b3_3;
    short8 b4_0, b4_1, b4_2, b4_3, b5_0, b5_1, b5_2, b5_3;
    short8 b6_0, b6_1, b6_2, b6_3, b7_0, b7_1, b7_2, b7_3;
#define LOADB(ks, nt) { \
    const float* s = g_enc + \
        (size_t)(wave * 64 + nt * 16 + (lane & 15)) * DMODEL + \
        ks * 32 + (lane >> 4) * 8; \
    b##ks##_##nt = cvt8(*reinterpret_cast<const f32x4*>(s), \
                        *reinterpret_cast<const f32x4*>(s + 4)); }
    LOADB(0,0) LOADB(0,1) LOADB(0,2) LOADB(0,3)
    LOADB(1,0) LOADB(1,1) LOADB(1,2) LOADB(1,3)
    LOADB(2,0) LOADB(2,1) LOADB(2,2) LOADB(2,3)
    LOADB(3,0) LOADB(3,1) LOADB(3,2) LOADB(3,3)
    LOADB(4,0) LOADB(4,1) LOADB(4,2) LOADB(4,3)
    LOADB(5,0) LOADB(5,1) LOADB(5,2) LOADB(5,3)
    LOADB(6,0) LOADB(6,1) LOADB(6,2) LOADB(6,3)
    LOADB(7,0) LOADB(7,1) LOADB(7,2) LOADB(7,3)
#undef LOADB

    char* abuf0 = lds_raw;
    char* abuf1 = lds_raw + 16 * ROW_STRIDE;

    // ---- prologue: stage tile 0 (wave stages rows 4w..4w+3) ----
    {
        const float* g = l_enc + (size_t)(row_blk + wave * 4) * DMODEL;
        f32x4 t0 = *reinterpret_cast<const f32x4*>(g + 0 * DMODEL + lane * 4);
        f32x4 t1 = *reinterpret_cast<const f32x4*>(g + 1 * DMODEL + lane * 4);
        f32x4 t2 = *reinterpret_cast<const f32x4*>(g + 2 * DMODEL + lane * 4);
        f32x4 t3 = *reinterpret_cast<const f32x4*>(g + 3 * DMODEL + lane * 4);
        *reinterpret_cast<f32x4*>(abuf0 + (wave * 4 + 0) * ROW_STRIDE + lane * 16) = t0;
        *reinterpret_cast<f32x4*>(abuf0 + (wave * 4 + 1) * ROW_STRIDE + lane * 16) = t1;
        *reinterpret_cast<f32x4*>(abuf0 + (wave * 4 + 2) * ROW_STRIDE + lane * 16) = t2;
        *reinterpret_cast<f32x4*>(abuf0 + (wave * 4 + 3) * ROW_STRIDE + lane * 16) = t3;
    }
    __syncthreads();

    double dS0 = 0.0, dS1 = 0.0, dS2 = 0.0;

#pragma unroll 1
    for (int p = 0; p < 32; ++p) {
        char* acur = (p & 1) ? abuf1 : abuf0;
        char* anxt = (p & 1) ? abuf0 : abuf1;
        const int rowbase = row_blk + p * 16;

        // issue next tile's global loads EARLY (HBM latency hides under
        // the MFMA+epilogue below; writes drain them late — T14 split)
        const int pn = (p + 1) & 31;
        const float* g = l_enc + (size_t)(row_blk + pn * 16 + wave * 4) * DMODEL;
        f32x4 t0 = *reinterpret_cast<const f32x4*>(g + 0 * DMODEL + lane * 4);
        f32x4 t1 = *reinterpret_cast<const f32x4*>(g + 1 * DMODEL + lane * 4);
        f32x4 t2 = *reinterpret_cast<const f32x4*>(g + 2 * DMODEL + lane * 4);
        f32x4 t3 = *reinterpret_cast<const f32x4*>(g + 3 * DMODEL + lane * 4);

        const int rsub = (lane >> 4) * 4;
        int bv0 = batch[rowbase + rsub + 0];
        int bv1 = batch[rowbase + rsub + 1];
        int bv2 = batch[rowbase + rsub + 2];
        int bv3 = batch[rowbase + rsub + 3];

        f32x4 acc0 = (f32x4){0.f, 0.f, 0.f, 0.f};
        f32x4 acc1 = (f32x4){0.f, 0.f, 0.f, 0.f};
        f32x4 acc2 = (f32x4){0.f, 0.f, 0.f, 0.f};
        f32x4 acc3 = (f32x4){0.f, 0.f, 0.f, 0.f};

        // A frag: row = lane&15, k-octet = lane>>4
        const char* ar = acur + (lane & 15) * ROW_STRIDE + (lane >> 4) * 32;
#define KSTEP(ks) { \
        f32x4 alo = *reinterpret_cast<const f32x4*>(ar + ks * 128); \
        f32x4 ahi = *reinterpret_cast<const f32x4*>(ar + ks * 128 + 16); \
        short8 a = cvt8(alo, ahi); \
        acc0 = __builtin_amdgcn_mfma_f32_16x16x32_bf16(a, b##ks##_0, acc0, 0, 0, 0); \
        acc1 = __builtin_amdgcn_mfma_f32_16x16x32_bf16(a, b##ks##_1, acc1, 0, 0, 0); \
        acc2 = __builtin_amdgcn_mfma_f32_16x16x32_bf16(a, b##ks##_2, acc2, 0, 0, 0); \
        acc3 = __builtin_amdgcn_mfma_f32_16x16x32_bf16(a, b##ks##_3, acc3, 0, 0, 0); }
        KSTEP(0) KSTEP(1) KSTEP(2) KSTEP(3)
        KSTEP(4) KSTEP(5) KSTEP(6) KSTEP(7)
#undef KSTEP

        // ---- lean epilogue (log2 units) ----
        // C/D: col = wave*64 + nt*16 + (lane&15), row = rowbase + rsub + rg
        float Sl2 = 0.f, Sl2p = 0.f, Spr = 0.f;
        const int colbase = wave * 64 + (lane & 15);
        {
            const int col = colbase + 0;
            elem(acc0[0], col, bv0, Sl2, Sl2p, Spr);
            elem(acc0[1], col, bv1, Sl2, Sl2p, Spr);
            elem(acc0[2], col, bv2, Sl2, Sl2p, Spr);
            elem(acc0[3], col, bv3, Sl2, Sl2p, Spr);
        }
        {
            const int col = colbase + 16;
            elem(acc1[0], col, bv0, Sl2, Sl2p, Spr);
            elem(acc1[1], col, bv1, Sl2, Sl2p, Spr);
            elem(acc1[2], col, bv2, Sl2, Sl2p, Spr);
            elem(acc1[3], col, bv3, Sl2, Sl2p, Spr);
        }
        {
            const int col = colbase + 32;
            elem(acc2[0], col, bv0, Sl2, Sl2p, Spr);
            elem(acc2[1], col, bv1, Sl2, Sl2p, Spr);
            elem(acc2[2], col, bv2, Sl2, Sl2p, Spr);
            elem(acc2[3], col, bv3, Sl2, Sl2p, Spr);
        }
        {
            const int col = colbase + 48;
            elem(acc3[0], col, bv0, Sl2, Sl2p, Spr);
            elem(acc3[1], col, bv1, Sl2, Sl2p, Spr);
            elem(acc3[2], col, bv2, Sl2, Sl2p, Spr);
            elem(acc3[3], col, bv3, Sl2, Sl2p, Spr);
        }
        dS0 += (double)Sl2;
        dS1 += (double)Sl2p;
        dS2 += (double)Spr;

        // write staged rows into the other buffer (its readers finished at
        // the barrier that closed pass p-1), then one barrier for pass p+1
        *reinterpret_cast<f32x4*>(anxt + (wave * 4 + 0) * ROW_STRIDE + lane * 16) = t0;
        *reinterpret_cast<f32x4*>(anxt + (wave * 4 + 1) * ROW_STRIDE + lane * 16) = t1;
        *reinterpret_cast<f32x4*>(anxt + (wave * 4 + 2) * ROW_STRIDE + lane * 16) = t2;
        *reinterpret_cast<f32x4*>(anxt + (wave * 4 + 3) * ROW_STRIDE + lane * 16) = t3;
        __syncthreads();
    }

    // ---- reduction: wave shuffle -> LDS -> block partial ----
#pragma unroll
    for (int off = 32; off; off >>= 1) {
        dS0 += __shfl_xor(dS0, off);
        dS1 += __shfl_xor(dS1, off);
        dS2 += __shfl_xor(dS2, off);
    }
    double* red = reinterpret_cast<double*>(lds_raw);
    if (lane == 0) {
        red[wave * 3 + 0] = dS0;
        red[wave * 3 + 1] = dS1;
        red[wave * 3 + 2] = dS2;
    }
    __syncthreads();
    if (tid == 0) {
        double a = 0, b = 0, c = 0;
#pragma unroll
        for (int w = 0; w < 4; ++w) {
            a += red[w * 3 + 0];
            b += red[w * 3 + 1];
            c += red[w * 3 + 2];
        }
        partials[bid * 3 + 0] = a;   // sum log2(1+2^t) (all)
        partials[bid * 3 + 1] = b;   // sum log2(1+2^t) (pos)
        partials[bid * 3 + 2] = c;   // sum r           (pos)
    }
}

__global__ void finalize_kernel(const double* __restrict__ p,
                                float* __restrict__ out) {
    int t = threadIdx.x;  // 512 threads, one partial-triple each
    double a = p[t * 3 + 0], b = p[t * 3 + 1], c = p[t * 3 + 2];
#pragma unroll
    for (int off = 32; off; off >>= 1) {
        a += __shfl_xor(a, off);
        b += __shfl_xor(b, off);
        c += __shfl_xor(c, off);
    }
    __shared__ double red[24];
    int lane = t & 63, w = t >> 6;
    if (lane == 0) { red[w * 3] = a; red[w * 3 + 1] = b; red[w * 3 + 2] = c; }
    __syncthreads();
    if (t == 0) {
        double A = 0, B = 0, C = 0;
#pragma unroll
        for (int i = 0; i < 8; ++i) {
            A += red[i * 3]; B += red[i * 3 + 1]; C += red[i * 3 + 2];
        }
        const double NN = (double)N_NODES, GG = (double)N_GRAPHS;
        double Sall_q = LN2 * A - NN * GG * LN2;
        double Spq = LN2 * B - NN * LN2;
        double Spr = C;
        double neg = (Sall_q - Spq) / (NN * (GG - 1.0));
        double pos = (Spr - Spq) / NN;
        out[0] = (float)(neg - pos);
    }
}

extern "C" void kernel_launch(void* const* d_in, const int* in_sizes, int n_in,
                              void* d_out, int out_size, void* d_ws,
                              size_t ws_size, hipStream_t stream) {
    const float* l_enc = (const float*)d_in[0];
    const float* g_enc = (const float*)d_in[1];
    const int* batch = (const int*)d_in[2];
    float* out = (float*)d_out;

    double* partials = (double*)d_ws;   // 512*3 doubles

    (void)hipFuncSetAttribute(reinterpret_cast<const void*>(mvgrl_main),
                              hipFuncAttributeMaxDynamicSharedMemorySize, 33280);

    mvgrl_main<<<512, 256, 33280, stream>>>(l_enc, g_enc, batch, partials);
    finalize_kernel<<<1, 512, 0, stream>>>(partials, out);
}

// Round 19
// 91.410 us; speedup vs baseline: 1.4922x; 1.3645x over previous
//
#include <hip/hip_runtime.h>
#include <hip/hip_bf16.h>

#define N_NODES 262144
#define N_GRAPHS 256
#define DMODEL 256
#define LN2 0.6931471805599453094

typedef __attribute__((ext_vector_type(4))) float f32x4;
typedef __attribute__((ext_vector_type(16))) float f32x16;
typedef __attribute__((ext_vector_type(8))) short short8;

__device__ __forceinline__ short bf(float x) {
    __hip_bfloat16 h = __float2bfloat16(x);
    return __builtin_bit_cast(short, h);
}

__device__ __forceinline__ short8 cvt8(f32x4 lo, f32x4 hi) {
    short8 a;
    a[0] = bf(lo[0]); a[1] = bf(lo[1]); a[2] = bf(lo[2]); a[3] = bf(lo[3]);
    a[4] = bf(hi[0]); a[5] = bf(hi[1]); a[6] = bf(hi[2]); a[7] = bf(hi[3]);
    return a;
}

// l2 = log2(1 + 2^(log2e*min(r,64)));  softplus(r) = ln2 * l2 (exact)
__device__ __forceinline__ void elem(float r, int col, int bv,
                                     float& Sl2, float& Sl2p, float& Spr) {
    float t = fminf(r, 64.f) * 1.44269504f;
    float l2 = __log2f(1.f + exp2f(t));
    Sl2 += l2;
    float m = (col == bv) ? 1.f : 0.f;
    Sl2p = fmaf(m, l2, Sl2p);
    Spr = fmaf(m, r, Spr);
}

// R19 = R15 skeleton (512 blocks x 256 thr, 2 phase-drifted blocks/CU,
// 64KB LDS = half of B, XCD-pair swizzle, NO main-loop barriers, group
// slot pipeline) with 32x32x16 MFMA: halves MFMA instr count AND
// ds_read_b128 count per FLOP (the two untested serial pipes).
// Wave: 32r x 128c per pass = 4 tiles of 32x32; acc = 4 x f32x16 (AGPRs).
// A-frag (m74 layout): lane l: row = l&31, k = kstep*16 + (l>>5)*8 + j.
// B-frag: lane l: col = l&31, same k. C/D: col = lane&31,
// row = (reg&3) + 8*(reg>>2) + 4*(lane>>5)  [m74/m101 verified].
__global__ __launch_bounds__(256, 1) void mvgrl_main(
    const float* __restrict__ l_enc, const float* __restrict__ g_enc,
    const int* __restrict__ batch, double* __restrict__ partials) {
    extern __shared__ char lds_raw[];  // 64KB: 64 chunks (ks*4+nt) of 1KB

    const int tid = threadIdx.x;
    const int lane = tid & 63;
    const int wave = tid >> 6;   // 0..3 = row stripe (32 rows each)
    const int bid = blockIdx.x;

    const int rg = (bid >> 4) * 8 + (bid & 7);  // row group 0..255
    const int chalf = (bid >> 3) & 1;           // column half
    const int row_blk = rg * 1024;
    const int alane = lane & 31;                // row within 32-row tile
    const int aoct = (lane >> 5) * 8;           // k-octet within 16-k step

    // ---- pass-0 A-slot preloads first (warm pipeline): ks 0..3 ----
    f32x4 s0l, s0h, s1l, s1h, s2l, s2h, s3l, s3h;
    const float* arow = l_enc +
        (size_t)(row_blk + wave * 32 + alane) * DMODEL + aoct;
    s0l = *reinterpret_cast<const f32x4*>(arow + 0);
    s0h = *reinterpret_cast<const f32x4*>(arow + 4);
    s1l = *reinterpret_cast<const f32x4*>(arow + 16);
    s1h = *reinterpret_cast<const f32x4*>(arow + 20);
    s2l = *reinterpret_cast<const f32x4*>(arow + 32);
    s2h = *reinterpret_cast<const f32x4*>(arow + 36);
    s3l = *reinterpret_cast<const f32x4*>(arow + 48);
    s3h = *reinterpret_cast<const f32x4*>(arow + 52);

    // ---- in-block B pack: our 128 cols -> LDS in 32x32x16 frag order ----
    // chunk c = ks*4 + nt (64 chunks, 1KB); within chunk lane*16B.
    {
        short8* lb = reinterpret_cast<short8*>(lds_raw);
#pragma unroll 2
        for (int i = 0; i < 16; ++i) {
            int c = wave + i * 4;          // 0..63
            int nt = c & 3, ks = c >> 2;
            int g = chalf * 128 + nt * 32 + (lane & 31);
            int k = ks * 16 + (lane >> 5) * 8;
            const float* src = g_enc + g * DMODEL + k;
            f32x4 lo = *reinterpret_cast<const f32x4*>(src);
            f32x4 hi = *reinterpret_cast<const f32x4*>(src + 4);
            lb[c * 64 + lane] = cvt8(lo, hi);
        }
    }
    __syncthreads();
    // no further barriers until final reduction

    const char* ldsB = lds_raw + lane * 16;
    double dS0 = 0.0, dS1 = 0.0, dS2 = 0.0;

#pragma unroll 1
    for (int pass = 0; pass < 8; ++pass) {
        const int rowbase = row_blk + pass * 128 + wave * 32;

        // 16 batch values per lane: row = rowbase + 4*(lane>>5) + rg + 8*oct
        const int hi4 = (lane >> 5) * 4;
        int bv[4][4];
#pragma unroll
        for (int oct = 0; oct < 4; ++oct)
#pragma unroll
            for (int r = 0; r < 4; ++r)
                bv[oct][r] = batch[rowbase + hi4 + r + 8 * oct];

        const float* arow_next = l_enc +
            (size_t)(row_blk + ((pass + 1) & 7) * 128 + wave * 32 + alane) *
                DMODEL + aoct;

        f32x16 acc0 = (f32x16)(0.f), acc1 = (f32x16)(0.f);
        f32x16 acc2 = (f32x16)(0.f), acc3 = (f32x16)(0.f);

#pragma unroll 1
        for (int g = 0; g < 4; ++g) {
            // group g consumes ks 4g..4g+3; refills with group g+1's data
            // (g=3 -> next pass ks0..3).
            const float* src = (g < 3) ? (arow + 64 * (g + 1)) : arow_next;
            const char* gb = ldsB + (size_t)g * 16384;
            {
                short8 a = cvt8(s0l, s0h);
                s0l = *reinterpret_cast<const f32x4*>(src + 0);
                s0h = *reinterpret_cast<const f32x4*>(src + 4);
                acc0 = __builtin_amdgcn_mfma_f32_32x32x16_bf16(a,
                    *reinterpret_cast<const short8*>(gb + 0 * 1024), acc0, 0, 0, 0);
                acc1 = __builtin_amdgcn_mfma_f32_32x32x16_bf16(a,
                    *reinterpret_cast<const short8*>(gb + 1 * 1024), acc1, 0, 0, 0);
                acc2 = __builtin_amdgcn_mfma_f32_32x32x16_bf16(a,
                    *reinterpret_cast<const short8*>(gb + 2 * 1024), acc2, 0, 0, 0);
                acc3 = __builtin_amdgcn_mfma_f32_32x32x16_bf16(a,
                    *reinterpret_cast<const short8*>(gb + 3 * 1024), acc3, 0, 0, 0);
            }
            {
                short8 a = cvt8(s1l, s1h);
                s1l = *reinterpret_cast<const f32x4*>(src + 16);
                s1h = *reinterpret_cast<const f32x4*>(src + 20);
                acc0 = __builtin_amdgcn_mfma_f32_32x32x16_bf16(a,
                    *reinterpret_cast<const short8*>(gb + 4 * 1024), acc0, 0, 0, 0);
                acc1 = __builtin_amdgcn_mfma_f32_32x32x16_bf16(a,
                    *reinterpret_cast<const short8*>(gb + 5 * 1024), acc1, 0, 0, 0);
                acc2 = __builtin_amdgcn_mfma_f32_32x32x16_bf16(a,
                    *reinterpret_cast<const short8*>(gb + 6 * 1024), acc2, 0, 0, 0);
                acc3 = __builtin_amdgcn_mfma_f32_32x32x16_bf16(a,
                    *reinterpret_cast<const short8*>(gb + 7 * 1024), acc3, 0, 0, 0);
            }
            {
                short8 a = cvt8(s2l, s2h);
                s2l = *reinterpret_cast<const f32x4*>(src + 32);
                s2h = *reinterpret_cast<const f32x4*>(src + 36);
                acc0 = __builtin_amdgcn_mfma_f32_32x32x16_bf16(a,
                    *reinterpret_cast<const short8*>(gb + 8 * 1024), acc0, 0, 0, 0);
                acc1 = __builtin_amdgcn_mfma_f32_32x32x16_bf16(a,
                    *reinterpret_cast<const short8*>(gb + 9 * 1024), acc1, 0, 0, 0);
                acc2 = __builtin_amdgcn_mfma_f32_32x32x16_bf16(a,
                    *reinterpret_cast<const short8*>(gb + 10 * 1024), acc2, 0, 0, 0);
                acc3 = __builtin_amdgcn_mfma_f32_32x32x16_bf16(a,
                    *reinterpret_cast<const short8*>(gb + 11 * 1024), acc3, 0, 0, 0);
            }
            {
                short8 a = cvt8(s3l, s3h);
                s3l = *reinterpret_cast<const f32x4*>(src + 48);
                s3h = *reinterpret_cast<const f32x4*>(src + 52);
                acc0 = __builtin_amdgcn_mfma_f32_32x32x16_bf16(a,
                    *reinterpret_cast<const short8*>(gb + 12 * 1024), acc0, 0, 0, 0);
                acc1 = __builtin_amdgcn_mfma_f32_32x32x16_bf16(a,
                    *reinterpret_cast<const short8*>(gb + 13 * 1024), acc1, 0, 0, 0);
                acc2 = __builtin_amdgcn_mfma_f32_32x32x16_bf16(a,
                    *reinterpret_cast<const short8*>(gb + 14 * 1024), acc2, 0, 0, 0);
                acc3 = __builtin_amdgcn_mfma_f32_32x32x16_bf16(a,
                    *reinterpret_cast<const short8*>(gb + 15 * 1024), acc3, 0, 0, 0);
            }
        }
        arow = arow_next;

        // ---- lean epilogue (log2 units) ----
        // col = chalf*128 + tile*32 + (lane&31)
        // row = rowbase + hi4 + (reg&3) + 8*(reg>>2)
        float Sl2 = 0.f, Sl2p = 0.f, Spr = 0.f;
        const int colb = chalf * 128 + (lane & 31);
#define EPI(accv, t)                                                      \
        {                                                                 \
            const int col = colb + t * 32;                                \
            _Pragma("unroll")                                             \
            for (int r = 0; r < 16; ++r)                                  \
                elem(accv[r], col, bv[r >> 2][r & 3], Sl2, Sl2p, Spr);    \
        }
        EPI(acc0, 0) EPI(acc1, 1) EPI(acc2, 2) EPI(acc3, 3)
#undef EPI
        dS0 += (double)Sl2;
        dS1 += (double)Sl2p;
        dS2 += (double)Spr;
    }

    // ---- reduction: wave shuffle -> LDS -> block partial ----
#pragma unroll
    for (int off = 32; off; off >>= 1) {
        dS0 += __shfl_xor(dS0, off);
        dS1 += __shfl_xor(dS1, off);
        dS2 += __shfl_xor(dS2, off);
    }
    __syncthreads();  // everyone done reading B before LDS reuse
    double* red = reinterpret_cast<double*>(lds_raw);
    if (lane == 0) {
        red[wave * 3 + 0] = dS0;
        red[wave * 3 + 1] = dS1;
        red[wave * 3 + 2] = dS2;
    }
    __syncthreads();
    if (tid == 0) {
        double a = 0, b = 0, c = 0;
#pragma unroll
        for (int w = 0; w < 4; ++w) {
            a += red[w * 3 + 0];
            b += red[w * 3 + 1];
            c += red[w * 3 + 2];
        }
        partials[bid * 3 + 0] = a;   // sum log2(1+2^t) (all)
        partials[bid * 3 + 1] = b;   // sum log2(1+2^t) (pos)
        partials[bid * 3 + 2] = c;   // sum r           (pos)
    }
}

__global__ void finalize_kernel(const double* __restrict__ p,
                                float* __restrict__ out) {
    int t = threadIdx.x;  // 512 threads, one partial-triple each
    double a = p[t * 3 + 0], b = p[t * 3 + 1], c = p[t * 3 + 2];
#pragma unroll
    for (int off = 32; off; off >>= 1) {
        a += __shfl_xor(a, off);
        b += __shfl_xor(b, off);
        c += __shfl_xor(c, off);
    }
    __shared__ double red[24];
    int lane = t & 63, w = t >> 6;
    if (lane == 0) { red[w * 3] = a; red[w * 3 + 1] = b; red[w * 3 + 2] = c; }
    __syncthreads();
    if (t == 0) {
        double A = 0, B = 0, C = 0;
#pragma unroll
        for (int i = 0; i < 8; ++i) {
            A += red[i * 3]; B += red[i * 3 + 1]; C += red[i * 3 + 2];
        }
        const double NN = (double)N_NODES, GG = (double)N_GRAPHS;
        double Sall_q = LN2 * A - NN * GG * LN2;
        double Spq = LN2 * B - NN * LN2;
        double Spr = C;
        double neg = (Sall_q - Spq) / (NN * (GG - 1.0));
        double pos = (Spr - Spq) / NN;
        out[0] = (float)(neg - pos);
    }
}

extern "C" void kernel_launch(void* const* d_in, const int* in_sizes, int n_in,
                              void* d_out, int out_size, void* d_ws,
                              size_t ws_size, hipStream_t stream) {
    const float* l_enc = (const float*)d_in[0];
    const float* g_enc = (const float*)d_in[1];
    const int* batch = (const int*)d_in[2];
    float* out = (float*)d_out;

    double* partials = (double*)d_ws;   // 512*3 doubles

    (void)hipFuncSetAttribute(reinterpret_cast<const void*>(mvgrl_main),
                              hipFuncAttributeMaxDynamicSharedMemorySize, 65536);

    mvgrl_main<<<512, 256, 65536, stream>>>(l_enc, g_enc, batch, partials);
    finalize_kernel<<<1, 512, 0, stream>>>(partials, out);
}